// Round 1
// baseline (1151.662 us; speedup 1.0000x reference)
//
#include <hip/hip_runtime.h>
#include <math.h>

#define BB 64
#define OO 32
#define II 2048
#define DD 16
#define CAPS_EPS 1e-12f

// t_const = ln(0.9*31) - ln(0.1) = ln(279)
#define T_CONST 5.6312118f

// workspace float offsets
#define OFF_DSUM 0                    // 2 floats (iter0, iter1 d-sums)
#define OFF_T    2                    // 2 floats (t0, t1)
#define OFF_V    16                   // 32768 floats: v [B][O][D]
#define OFF_D    (16 + 32768)         // 4194304 floats: d [I][B][O]
#define OFF_PART ((size_t)OFF_D + (size_t)BB*OO*II)  // ICHUNKS*32768 floats

__global__ void init_kernel(float* ws) {
    if (threadIdx.x == 0 && blockIdx.x == 0) {
        ws[OFF_DSUM + 0] = 0.f;
        ws[OFF_DSUM + 1] = 0.f;
    }
}

// STAGE 0: s0 partials (c = 1/32)
// STAGE 1: d0 = ||v0 - u_hat||, store d, accumulate sum -> dsum[0]
// STAGE 2: c1 = softmax(t0*d0) over o, s1 partials
// STAGE 3: d1, dsum[1]
// STAGE 4: c2 = softmax(t1*d1), write c2 to out, s2 partials
template<int STAGE>
__global__ __launch_bounds__(256) void stage_kernel(
    const float* __restrict__ u,   // [B][I][16]
    const float* __restrict__ W,   // [O][I][16][16]
    float* __restrict__ ws,
    float* __restrict__ c_out,     // [B][O][I]
    int TI)
{
    const int ic   = blockIdx.x;            // i-chunk
    const int og2  = blockIdx.y;            // o-half (0/1)
    const int wave = threadIdx.x >> 6;      // 0..3
    const int b    = threadIdx.x & 63;      // lane = batch index
    const int o_base = og2 * 16 + wave * 4; // 4 o's per wave

    float* part       = ws + OFF_PART;
    float* d_ws       = ws + OFF_D;
    const float* v_ws = ws + OFF_V;

    float s_acc[4][DD];
    if (STAGE == 0 || STAGE == 2 || STAGE == 4) {
        #pragma unroll
        for (int ol = 0; ol < 4; ++ol)
            #pragma unroll
            for (int d = 0; d < DD; ++d) s_acc[ol][d] = 0.f;
    }

    float vreg[4][DD];
    if (STAGE == 1 || STAGE == 3) {
        #pragma unroll
        for (int ol = 0; ol < 4; ++ol) {
            const float4* vp = reinterpret_cast<const float4*>(
                v_ws + ((size_t)b * OO + o_base + ol) * DD);
            #pragma unroll
            for (int q = 0; q < 4; ++q) {
                float4 t4 = vp[q];
                vreg[ol][4*q+0] = t4.x; vreg[ol][4*q+1] = t4.y;
                vreg[ol][4*q+2] = t4.z; vreg[ol][4*q+3] = t4.w;
            }
        }
    }

    float tval = 0.f;
    if (STAGE == 2) tval = ws[OFF_T + 0];
    if (STAGE == 4) tval = ws[OFF_T + 1];

    float dsum_local = 0.f;

    for (int ii = 0; ii < TI; ++ii) {
        const int i = ic * TI + ii;

        // load u[b][i][:] into registers
        float ureg[DD];
        {
            const float4* up = reinterpret_cast<const float4*>(
                u + ((size_t)b * II + i) * DD);
            #pragma unroll
            for (int q = 0; q < 4; ++q) {
                float4 t4 = up[q];
                ureg[4*q+0] = t4.x; ureg[4*q+1] = t4.y;
                ureg[4*q+2] = t4.z; ureg[4*q+3] = t4.w;
            }
        }
        float un2 = 0.f;
        #pragma unroll
        for (int k = 0; k < DD; ++k) un2 += ureg[k] * ureg[k];
        const float unorm = sqrtf(un2);

        // softmax over o (stages 2,4)
        float c_here[4];
        if (STAGE == 2 || STAGE == 4) {
            const float4* dp = reinterpret_cast<const float4*>(
                d_ws + ((size_t)i * BB + b) * OO);
            float bv[OO];
            #pragma unroll
            for (int q = 0; q < 8; ++q) {
                float4 t4 = dp[q];
                bv[4*q+0] = tval * t4.x; bv[4*q+1] = tval * t4.y;
                bv[4*q+2] = tval * t4.z; bv[4*q+3] = tval * t4.w;
            }
            float m = -1e30f;
            #pragma unroll
            for (int o = 0; o < OO; ++o) m = fmaxf(m, bv[o]);
            float ssum = 0.f;
            #pragma unroll
            for (int o = 0; o < OO; ++o) { bv[o] = __expf(bv[o] - m); ssum += bv[o]; }
            const float inv = 1.f / ssum;
            #pragma unroll
            for (int ol = 0; ol < 4; ++ol) c_here[ol] = bv[o_base + ol] * inv;
            if (STAGE == 4) {
                #pragma unroll
                for (int ol = 0; ol < 4; ++ol)
                    c_out[((size_t)b * OO + o_base + ol) * II + i] = c_here[ol];
            }
        }

        #pragma unroll
        for (int ol = 0; ol < 4; ++ol) {
            const int o = o_base + ol;
            const float4* wp = reinterpret_cast<const float4*>(
                W + ((size_t)o * II + i) * (DD * DD));
            float uh[DD];
            float n2 = 0.f;
            #pragma unroll
            for (int d2 = 0; d2 < DD; ++d2) {
                float acc = 0.f;
                #pragma unroll
                for (int q = 0; q < 4; ++q) {
                    float4 w4 = wp[d2 * 4 + q];
                    acc += w4.x * ureg[4*q+0] + w4.y * ureg[4*q+1]
                         + w4.z * ureg[4*q+2] + w4.w * ureg[4*q+3];
                }
                uh[d2] = acc;
                n2 += acc * acc;
            }
            const float rawn  = sqrtf(n2);
            const float scale = fminf(rawn, unorm) / (rawn + CAPS_EPS);

            if (STAGE == 0 || STAGE == 2 || STAGE == 4) {
                const float cc = (STAGE == 0) ? (1.0f / OO) : c_here[ol];
                const float cs = cc * scale;
                #pragma unroll
                for (int d = 0; d < DD; ++d) s_acc[ol][d] += cs * uh[d];
            } else {
                float dist2 = 0.f;
                #pragma unroll
                for (int d = 0; d < DD; ++d) {
                    float df = vreg[ol][d] - scale * uh[d];
                    dist2 += df * df;
                }
                const float dist = sqrtf(dist2);
                d_ws[((size_t)i * BB + b) * OO + o] = dist;
                dsum_local += dist;
            }
        }
    }

    if (STAGE == 0 || STAGE == 2 || STAGE == 4) {
        #pragma unroll
        for (int ol = 0; ol < 4; ++ol)
            #pragma unroll
            for (int d = 0; d < DD; ++d)
                part[(((size_t)ic * BB + b) * OO + o_base + ol) * DD + d] = s_acc[ol][d];
    } else {
        #pragma unroll
        for (int off = 32; off > 0; off >>= 1)
            dsum_local += __shfl_down(dsum_local, off);
        __shared__ float red[4];
        if (b == 0) red[wave] = dsum_local;
        __syncthreads();
        if (threadIdx.x == 0) {
            float t = red[0] + red[1] + red[2] + red[3];
            atomicAdd(&ws[OFF_DSUM + (STAGE == 1 ? 0 : 1)], t);
        }
    }
}

// reduce s-partials (+bias) -> squash -> v. 32768 threads, grid 128x256.
__global__ __launch_bounds__(256) void finv_kernel(
    const float* __restrict__ part, const float* __restrict__ bias,
    float* __restrict__ vout, int ICHUNKS)
{
    const int tid = blockIdx.x * 256 + threadIdx.x;  // b*512 + o*16 + d
    float s = 0.f;
    for (int ic = 0; ic < ICHUNKS; ++ic) s += part[(size_t)ic * 32768 + tid];
    s += bias[tid & 511];
    float n2 = s * s;
    #pragma unroll
    for (int off = 1; off < 16; off <<= 1) n2 += __shfl_xor(n2, off);
    const float val = s * (n2 / (1.f + n2)) * rsqrtf(n2 + CAPS_EPS);
    vout[tid] = val;
}

__global__ void fint_kernel(float* ws, int slot) {
    if (threadIdx.x == 0 && blockIdx.x == 0) {
        const float d_o = ws[OFF_DSUM + slot] * (1.0f / (float)((size_t)BB * OO * II));
        // d_p - d_o = -0.5*d_o
        ws[OFF_T + slot] = T_CONST / (-0.5f * d_o + 1e-12f);
    }
}

extern "C" void kernel_launch(void* const* d_in, const int* in_sizes, int n_in,
                              void* d_out, int out_size, void* d_ws, size_t ws_size,
                              hipStream_t stream) {
    const float* u    = (const float*)d_in[0];
    const float* W    = (const float*)d_in[1];
    const float* bias = (const float*)d_in[2];
    float* out = (float*)d_out;
    float* ws  = (float*)d_ws;

    // pick ICHUNKS so OFF_PART + ICHUNKS*32768 floats fits in ws
    size_t avail = ws_size / 4;
    int ICHUNKS = 256;
    while (ICHUNKS > 1 && (OFF_PART + (size_t)ICHUNKS * 32768) > avail) ICHUNKS >>= 1;
    const int TI = II / ICHUNKS;

    float* part = ws + OFF_PART;
    float* v_ws = ws + OFF_V;
    float* cout = out + (size_t)BB * OO * DD;  // c_ij after v_j (32768 floats)

    dim3 grid(ICHUNKS, 2), blk(256);

    init_kernel<<<1, 64, 0, stream>>>(ws);
    stage_kernel<0><<<grid, blk, 0, stream>>>(u, W, ws, cout, TI);
    finv_kernel<<<128, 256, 0, stream>>>(part, bias, v_ws, ICHUNKS);
    stage_kernel<1><<<grid, blk, 0, stream>>>(u, W, ws, cout, TI);
    fint_kernel<<<1, 64, 0, stream>>>(ws, 0);
    stage_kernel<2><<<grid, blk, 0, stream>>>(u, W, ws, cout, TI);
    finv_kernel<<<128, 256, 0, stream>>>(part, bias, v_ws, ICHUNKS);
    stage_kernel<3><<<grid, blk, 0, stream>>>(u, W, ws, cout, TI);
    fint_kernel<<<1, 64, 0, stream>>>(ws, 1);
    stage_kernel<4><<<grid, blk, 0, stream>>>(u, W, ws, cout, TI);
    finv_kernel<<<128, 256, 0, stream>>>(part, bias, out, ICHUNKS);
}

// Round 2
// 767.899 us; speedup vs baseline: 1.4998x; 1.4998x over previous
//
#include <hip/hip_runtime.h>
#include <hip/hip_bf16.h>
#include <math.h>

#define BB 64
#define OO 32
#define II 2048
#define DD 16
#define CAPS_EPS 1e-12f

// t_const = ln(0.9*31) - ln(0.1) = ln(279)
#define T_CONST 5.6312118f

// workspace float offsets
#define OFF_DSUM 0ULL                        // 2 floats (iter0, iter1 d-sums)
#define OFF_T    2ULL                        // 2 floats (t0, t1)
#define OFF_V    16ULL                       // 32768 floats: v [B][O][D]
#define OFF_D    (16ULL + 32768ULL)          // 4194304 floats: d [I][B][O]
#define OFF_PART (OFF_D + (size_t)BB*OO*II)  // up to 512*32768 floats (fallback) / 256*32768 (mat)
#define OFF_CT   (OFF_PART + 256ULL*32768ULL)   // 4194304 floats: c temp [I][B][O]
#define OFF_UHAT (OFF_CT + 4194304ULL)          // 67108864 bf16 (= 33554432 float slots)
#define NEED_MAT_BYTES (OFF_UHAT*4ULL + 67108864ULL*2ULL)  // 201,457,728 B

__device__ __forceinline__ float bf16_lo(unsigned v) {
    union { unsigned u; float f; } c; c.u = v << 16; return c.f;
}
__device__ __forceinline__ float bf16_hi(unsigned v) {
    union { unsigned u; float f; } c; c.u = v & 0xffff0000u; return c.f;
}
__device__ __forceinline__ unsigned pack_bf16(float a, float b) {
    __hip_bfloat16 ha = __float2bfloat16(a), hb = __float2bfloat16(b);
    unsigned short sa, sb;
    __builtin_memcpy(&sa, &ha, 2); __builtin_memcpy(&sb, &hb, 2);
    return (unsigned)sa | ((unsigned)sb << 16);
}

__global__ void init_kernel(float* ws) {
    if (threadIdx.x == 0 && blockIdx.x == 0) {
        ws[OFF_DSUM + 0] = 0.f;
        ws[OFF_DSUM + 1] = 0.f;
    }
}

// ---------------- materialized path ----------------

// Computes scaled u_hat (bf16, layout [I][B][O][D]) and s0 partials (c = 1/32).
__global__ __launch_bounds__(256) void uhat_kernel(
    const float* __restrict__ u,   // [B][I][16]
    const float* __restrict__ W,   // [O][I][16][16]
    unsigned* __restrict__ uhat,   // [I][B][O][8] packed bf16 pairs
    float* __restrict__ part, int TI)
{
    const int ic   = blockIdx.x;
    const int og2  = blockIdx.y;
    const int wave = threadIdx.x >> 6;
    const int b    = threadIdx.x & 63;
    const int o_base = og2 * 16 + wave * 4;

    float s_acc[4][DD];
    #pragma unroll
    for (int ol = 0; ol < 4; ++ol)
        #pragma unroll
        for (int d = 0; d < DD; ++d) s_acc[ol][d] = 0.f;

    for (int ii = 0; ii < TI; ++ii) {
        const int i = ic * TI + ii;

        float ureg[DD];
        {
            const float4* up = reinterpret_cast<const float4*>(
                u + ((size_t)b * II + i) * DD);
            #pragma unroll
            for (int q = 0; q < 4; ++q) {
                float4 t4 = up[q];
                ureg[4*q+0] = t4.x; ureg[4*q+1] = t4.y;
                ureg[4*q+2] = t4.z; ureg[4*q+3] = t4.w;
            }
        }
        float un2 = 0.f;
        #pragma unroll
        for (int k = 0; k < DD; ++k) un2 += ureg[k] * ureg[k];
        const float unorm = sqrtf(un2);

        #pragma unroll
        for (int ol = 0; ol < 4; ++ol) {
            // wave-uniform o -> scalar (s_load) W fetch
            const int o_u = __builtin_amdgcn_readfirstlane(o_base + ol);
            const float4* wp = reinterpret_cast<const float4*>(
                W + ((size_t)o_u * II + i) * (DD * DD));
            float uh[DD];
            float n2 = 0.f;
            #pragma unroll
            for (int d2 = 0; d2 < DD; ++d2) {
                float acc = 0.f;
                #pragma unroll
                for (int q = 0; q < 4; ++q) {
                    float4 w4 = wp[d2 * 4 + q];
                    acc += w4.x * ureg[4*q+0] + w4.y * ureg[4*q+1]
                         + w4.z * ureg[4*q+2] + w4.w * ureg[4*q+3];
                }
                uh[d2] = acc;
                n2 += acc * acc;
            }
            const float rawn  = sqrtf(n2);
            const float scale = fminf(rawn, unorm) / (rawn + CAPS_EPS);
            #pragma unroll
            for (int d = 0; d < DD; ++d) {
                uh[d] *= scale;
                s_acc[ol][d] += uh[d];
            }
            // store packed bf16, 32 B contiguous per (o)
            unsigned* outp = uhat + ((((size_t)i * BB + b) * OO) + o_base + ol) * 8;
            uint4 p0, p1;
            p0.x = pack_bf16(uh[0],  uh[1]);  p0.y = pack_bf16(uh[2],  uh[3]);
            p0.z = pack_bf16(uh[4],  uh[5]);  p0.w = pack_bf16(uh[6],  uh[7]);
            p1.x = pack_bf16(uh[8],  uh[9]);  p1.y = pack_bf16(uh[10], uh[11]);
            p1.z = pack_bf16(uh[12], uh[13]); p1.w = pack_bf16(uh[14], uh[15]);
            reinterpret_cast<uint4*>(outp)[0] = p0;
            reinterpret_cast<uint4*>(outp)[1] = p1;
        }
    }

    #pragma unroll
    for (int ol = 0; ol < 4; ++ol)
        #pragma unroll
        for (int d = 0; d < DD; ++d)
            part[(((size_t)ic * BB + b) * OO + o_base + ol) * DD + d] =
                s_acc[ol][d] * (1.0f / OO);
}

// STAGE 1: d0 = ||v0 - u_hat||, store d, dsum[0]
// STAGE 2: c1 = softmax(t0*d0), s1 partials
// STAGE 3: d1, dsum[1]
// STAGE 4: c2 = softmax(t1*d1), write c to ct ([I][B][O]), s2 partials
template<int STAGE>
__global__ __launch_bounds__(256) void mstage_kernel(
    const unsigned* __restrict__ uhat,
    float* __restrict__ ws,
    float* __restrict__ part,
    float* __restrict__ ct,
    int TI)
{
    const int ic   = blockIdx.x;
    const int og2  = blockIdx.y;
    const int wave = threadIdx.x >> 6;
    const int b    = threadIdx.x & 63;
    const int o_base = og2 * 16 + wave * 4;

    float* d_ws       = ws + OFF_D;
    const float* v_ws = ws + OFF_V;

    float s_acc[4][DD];
    if (STAGE == 2 || STAGE == 4) {
        #pragma unroll
        for (int ol = 0; ol < 4; ++ol)
            #pragma unroll
            for (int d = 0; d < DD; ++d) s_acc[ol][d] = 0.f;
    }

    float vreg[4][DD];
    if (STAGE == 1 || STAGE == 3) {
        #pragma unroll
        for (int ol = 0; ol < 4; ++ol) {
            const float4* vp = reinterpret_cast<const float4*>(
                v_ws + ((size_t)b * OO + o_base + ol) * DD);
            #pragma unroll
            for (int q = 0; q < 4; ++q) {
                float4 t4 = vp[q];
                vreg[ol][4*q+0] = t4.x; vreg[ol][4*q+1] = t4.y;
                vreg[ol][4*q+2] = t4.z; vreg[ol][4*q+3] = t4.w;
            }
        }
    }

    float tval = 0.f;
    if (STAGE == 2) tval = ws[OFF_T + 0];
    if (STAGE == 4) tval = ws[OFF_T + 1];

    float dsum_local = 0.f;

    for (int ii = 0; ii < TI; ++ii) {
        const int i = ic * TI + ii;

        // load u_hat for 4 o's: 128 B contiguous per lane
        uint4 q[8];
        {
            const uint4* up = reinterpret_cast<const uint4*>(
                uhat + (((size_t)i * BB + b) * OO + o_base) * 8);
            #pragma unroll
            for (int j = 0; j < 8; ++j) q[j] = up[j];
        }

        float c_here[4];
        if (STAGE == 2 || STAGE == 4) {
            const float4* dp = reinterpret_cast<const float4*>(
                d_ws + ((size_t)i * BB + b) * OO);
            float bv[OO];
            #pragma unroll
            for (int qq = 0; qq < 8; ++qq) {
                float4 t4 = dp[qq];
                bv[4*qq+0] = tval * t4.x; bv[4*qq+1] = tval * t4.y;
                bv[4*qq+2] = tval * t4.z; bv[4*qq+3] = tval * t4.w;
            }
            float m = -1e30f;
            #pragma unroll
            for (int o = 0; o < OO; ++o) m = fmaxf(m, bv[o]);
            float ssum = 0.f;
            #pragma unroll
            for (int o = 0; o < OO; ++o) { bv[o] = __expf(bv[o] - m); ssum += bv[o]; }
            const float inv = 1.f / ssum;
            #pragma unroll
            for (int ol = 0; ol < 4; ++ol) c_here[ol] = bv[o_base + ol] * inv;
            if (STAGE == 4) {
                float4 cw = make_float4(c_here[0], c_here[1], c_here[2], c_here[3]);
                *reinterpret_cast<float4*>(
                    ct + ((size_t)i * BB + b) * OO + o_base) = cw;
            }
        }

        #pragma unroll
        for (int ol = 0; ol < 4; ++ol) {
            float uh[DD];
            #pragma unroll
            for (int j = 0; j < 4; ++j) {
                unsigned w0 = (&q[2*ol].x)[j];
                uh[2*j+0] = bf16_lo(w0);
                uh[2*j+1] = bf16_hi(w0);
                unsigned w1 = (&q[2*ol+1].x)[j];
                uh[8+2*j+0] = bf16_lo(w1);
                uh[8+2*j+1] = bf16_hi(w1);
            }
            if (STAGE == 2 || STAGE == 4) {
                const float cc = c_here[ol];
                #pragma unroll
                for (int d = 0; d < DD; ++d) s_acc[ol][d] += cc * uh[d];
            } else {
                float dist2 = 0.f;
                #pragma unroll
                for (int d = 0; d < DD; ++d) {
                    float df = vreg[ol][d] - uh[d];
                    dist2 += df * df;
                }
                const float dist = sqrtf(dist2);
                d_ws[((size_t)i * BB + b) * OO + o_base + ol] = dist;
                dsum_local += dist;
            }
        }
    }

    if (STAGE == 2 || STAGE == 4) {
        #pragma unroll
        for (int ol = 0; ol < 4; ++ol)
            #pragma unroll
            for (int d = 0; d < DD; ++d)
                part[(((size_t)ic * BB + b) * OO + o_base + ol) * DD + d] = s_acc[ol][d];
    } else {
        #pragma unroll
        for (int off = 32; off > 0; off >>= 1)
            dsum_local += __shfl_down(dsum_local, off);
        __shared__ float red[4];
        if (b == 0) red[wave] = dsum_local;
        __syncthreads();
        if (threadIdx.x == 0) {
            float t = red[0] + red[1] + red[2] + red[3];
            atomicAdd(&ws[OFF_DSUM + (STAGE == 1 ? 0 : 1)], t);
        }
    }
}

// ct [I][J] (J = b*32+o, both 2048) -> out [J][I], LDS-tiled transpose
__global__ __launch_bounds__(256) void transpose_kernel(
    const float* __restrict__ src, float* __restrict__ dst)
{
    __shared__ float tile[32][33];
    const int tx = threadIdx.x & 31;
    const int ty = threadIdx.x >> 5;   // 0..7
    const int i0 = blockIdx.y * 32;
    const int j0 = blockIdx.x * 32;
    #pragma unroll
    for (int k = 0; k < 4; ++k)
        tile[ty + k*8][tx] = src[(size_t)(i0 + ty + k*8) * 2048 + j0 + tx];
    __syncthreads();
    #pragma unroll
    for (int k = 0; k < 4; ++k)
        dst[(size_t)(j0 + ty + k*8) * 2048 + i0 + tx] = tile[tx][ty + k*8];
}

// ---------------- fallback (recompute) path ----------------

template<int STAGE>
__global__ __launch_bounds__(256) void stage_kernel(
    const float* __restrict__ u,
    const float* __restrict__ W,
    float* __restrict__ ws,
    float* __restrict__ c_out,
    int TI)
{
    const int ic   = blockIdx.x;
    const int og2  = blockIdx.y;
    const int wave = threadIdx.x >> 6;
    const int b    = threadIdx.x & 63;
    const int o_base = og2 * 16 + wave * 4;

    float* part       = ws + OFF_PART;
    float* d_ws       = ws + OFF_D;
    const float* v_ws = ws + OFF_V;

    float s_acc[4][DD];
    if (STAGE == 0 || STAGE == 2 || STAGE == 4) {
        #pragma unroll
        for (int ol = 0; ol < 4; ++ol)
            #pragma unroll
            for (int d = 0; d < DD; ++d) s_acc[ol][d] = 0.f;
    }

    float vreg[4][DD];
    if (STAGE == 1 || STAGE == 3) {
        #pragma unroll
        for (int ol = 0; ol < 4; ++ol) {
            const float4* vp = reinterpret_cast<const float4*>(
                v_ws + ((size_t)b * OO + o_base + ol) * DD);
            #pragma unroll
            for (int q = 0; q < 4; ++q) {
                float4 t4 = vp[q];
                vreg[ol][4*q+0] = t4.x; vreg[ol][4*q+1] = t4.y;
                vreg[ol][4*q+2] = t4.z; vreg[ol][4*q+3] = t4.w;
            }
        }
    }

    float tval = 0.f;
    if (STAGE == 2) tval = ws[OFF_T + 0];
    if (STAGE == 4) tval = ws[OFF_T + 1];

    float dsum_local = 0.f;

    for (int ii = 0; ii < TI; ++ii) {
        const int i = ic * TI + ii;

        float ureg[DD];
        {
            const float4* up = reinterpret_cast<const float4*>(
                u + ((size_t)b * II + i) * DD);
            #pragma unroll
            for (int q = 0; q < 4; ++q) {
                float4 t4 = up[q];
                ureg[4*q+0] = t4.x; ureg[4*q+1] = t4.y;
                ureg[4*q+2] = t4.z; ureg[4*q+3] = t4.w;
            }
        }
        float un2 = 0.f;
        #pragma unroll
        for (int k = 0; k < DD; ++k) un2 += ureg[k] * ureg[k];
        const float unorm = sqrtf(un2);

        float c_here[4];
        if (STAGE == 2 || STAGE == 4) {
            const float4* dp = reinterpret_cast<const float4*>(
                d_ws + ((size_t)i * BB + b) * OO);
            float bv[OO];
            #pragma unroll
            for (int q = 0; q < 8; ++q) {
                float4 t4 = dp[q];
                bv[4*q+0] = tval * t4.x; bv[4*q+1] = tval * t4.y;
                bv[4*q+2] = tval * t4.z; bv[4*q+3] = tval * t4.w;
            }
            float m = -1e30f;
            #pragma unroll
            for (int o = 0; o < OO; ++o) m = fmaxf(m, bv[o]);
            float ssum = 0.f;
            #pragma unroll
            for (int o = 0; o < OO; ++o) { bv[o] = __expf(bv[o] - m); ssum += bv[o]; }
            const float inv = 1.f / ssum;
            #pragma unroll
            for (int ol = 0; ol < 4; ++ol) c_here[ol] = bv[o_base + ol] * inv;
            if (STAGE == 4) {
                #pragma unroll
                for (int ol = 0; ol < 4; ++ol)
                    c_out[((size_t)b * OO + o_base + ol) * II + i] = c_here[ol];
            }
        }

        #pragma unroll
        for (int ol = 0; ol < 4; ++ol) {
            const int o_u = __builtin_amdgcn_readfirstlane(o_base + ol);
            const float4* wp = reinterpret_cast<const float4*>(
                W + ((size_t)o_u * II + i) * (DD * DD));
            float uh[DD];
            float n2 = 0.f;
            #pragma unroll
            for (int d2 = 0; d2 < DD; ++d2) {
                float acc = 0.f;
                #pragma unroll
                for (int q = 0; q < 4; ++q) {
                    float4 w4 = wp[d2 * 4 + q];
                    acc += w4.x * ureg[4*q+0] + w4.y * ureg[4*q+1]
                         + w4.z * ureg[4*q+2] + w4.w * ureg[4*q+3];
                }
                uh[d2] = acc;
                n2 += acc * acc;
            }
            const float rawn  = sqrtf(n2);
            const float scale = fminf(rawn, unorm) / (rawn + CAPS_EPS);

            if (STAGE == 0 || STAGE == 2 || STAGE == 4) {
                const float cc = (STAGE == 0) ? (1.0f / OO) : c_here[ol];
                const float cs = cc * scale;
                #pragma unroll
                for (int d = 0; d < DD; ++d) s_acc[ol][d] += cs * uh[d];
            } else {
                float dist2 = 0.f;
                #pragma unroll
                for (int d = 0; d < DD; ++d) {
                    float df = vreg[ol][d] - scale * uh[d];
                    dist2 += df * df;
                }
                const float dist = sqrtf(dist2);
                d_ws[((size_t)i * BB + b) * OO + o_base + wave - wave + (o_u - o_base) + o_base - o_base + (o_base + ol) - o_base] = dist;  // = o_base+ol
                dsum_local += dist;
            }
        }
    }

    if (STAGE == 0 || STAGE == 2 || STAGE == 4) {
        #pragma unroll
        for (int ol = 0; ol < 4; ++ol)
            #pragma unroll
            for (int d = 0; d < DD; ++d)
                part[(((size_t)ic * BB + b) * OO + o_base + ol) * DD + d] = s_acc[ol][d];
    } else {
        #pragma unroll
        for (int off = 32; off > 0; off >>= 1)
            dsum_local += __shfl_down(dsum_local, off);
        __shared__ float red[4];
        if (b == 0) red[wave] = dsum_local;
        __syncthreads();
        if (threadIdx.x == 0) {
            float t = red[0] + red[1] + red[2] + red[3];
            atomicAdd(&ws[OFF_DSUM + (STAGE == 1 ? 0 : 1)], t);
        }
    }
}

// ---------------- shared finalize kernels ----------------

__global__ __launch_bounds__(256) void finv_kernel(
    const float* __restrict__ part, const float* __restrict__ bias,
    float* __restrict__ vout, int ICHUNKS)
{
    const int tid = blockIdx.x * 256 + threadIdx.x;  // b*512 + o*16 + d
    float s = 0.f;
    for (int ic = 0; ic < ICHUNKS; ++ic) s += part[(size_t)ic * 32768 + tid];
    s += bias[tid & 511];
    float n2 = s * s;
    #pragma unroll
    for (int off = 1; off < 16; off <<= 1) n2 += __shfl_xor(n2, off);
    const float val = s * (n2 / (1.f + n2)) * rsqrtf(n2 + CAPS_EPS);
    vout[tid] = val;
}

__global__ void fint_kernel(float* ws, int slot) {
    if (threadIdx.x == 0 && blockIdx.x == 0) {
        const float d_o = ws[OFF_DSUM + slot] * (1.0f / (float)((size_t)BB * OO * II));
        ws[OFF_T + slot] = T_CONST / (-0.5f * d_o + 1e-12f);
    }
}

extern "C" void kernel_launch(void* const* d_in, const int* in_sizes, int n_in,
                              void* d_out, int out_size, void* d_ws, size_t ws_size,
                              hipStream_t stream) {
    const float* u    = (const float*)d_in[0];
    const float* W    = (const float*)d_in[1];
    const float* bias = (const float*)d_in[2];
    float* out = (float*)d_out;
    float* ws  = (float*)d_ws;

    float* part = ws + OFF_PART;
    float* v_ws = ws + OFF_V;
    float* cout = out + (size_t)BB * OO * DD;

    if (ws_size >= NEED_MAT_BYTES) {
        // materialized bf16 u_hat path
        float*    ct   = ws + OFF_CT;
        unsigned* uhat = (unsigned*)(ws + OFF_UHAT);
        const int ICH = 256, TI = II / ICH;
        dim3 grid(ICH, 2), blk(256);

        init_kernel<<<1, 64, 0, stream>>>(ws);
        uhat_kernel<<<grid, blk, 0, stream>>>(u, W, uhat, part, TI);
        finv_kernel<<<128, 256, 0, stream>>>(part, bias, v_ws, ICH);
        mstage_kernel<1><<<grid, blk, 0, stream>>>(uhat, ws, part, ct, TI);
        fint_kernel<<<1, 64, 0, stream>>>(ws, 0);
        mstage_kernel<2><<<grid, blk, 0, stream>>>(uhat, ws, part, ct, TI);
        finv_kernel<<<128, 256, 0, stream>>>(part, bias, v_ws, ICH);
        mstage_kernel<3><<<grid, blk, 0, stream>>>(uhat, ws, part, ct, TI);
        fint_kernel<<<1, 64, 0, stream>>>(ws, 1);
        mstage_kernel<4><<<grid, blk, 0, stream>>>(uhat, ws, part, ct, TI);
        finv_kernel<<<128, 256, 0, stream>>>(part, bias, out, ICH);
        transpose_kernel<<<dim3(64, 64), 256, 0, stream>>>(ct, cout);
    } else {
        // fallback: recompute path (with uniform-W scalar loads)
        size_t availF = ws_size / 4;
        int ICHUNKS = 512;
        while (ICHUNKS > 1 && (OFF_PART + (size_t)ICHUNKS * 32768) > availF) ICHUNKS >>= 1;
        const int TI = II / ICHUNKS;
        dim3 grid(ICHUNKS, 2), blk(256);

        init_kernel<<<1, 64, 0, stream>>>(ws);
        stage_kernel<0><<<grid, blk, 0, stream>>>(u, W, ws, cout, TI);
        finv_kernel<<<128, 256, 0, stream>>>(part, bias, v_ws, ICHUNKS);
        stage_kernel<1><<<grid, blk, 0, stream>>>(u, W, ws, cout, TI);
        fint_kernel<<<1, 64, 0, stream>>>(ws, 0);
        stage_kernel<2><<<grid, blk, 0, stream>>>(u, W, ws, cout, TI);
        finv_kernel<<<128, 256, 0, stream>>>(part, bias, v_ws, ICHUNKS);
        stage_kernel<3><<<grid, blk, 0, stream>>>(u, W, ws, cout, TI);
        fint_kernel<<<1, 64, 0, stream>>>(ws, 1);
        stage_kernel<4><<<grid, blk, 0, stream>>>(u, W, ws, cout, TI);
        finv_kernel<<<128, 256, 0, stream>>>(part, bias, out, ICHUNKS);
    }
}